// Round 7
// baseline (862.434 us; speedup 1.0000x reference)
//
#include <hip/hip_runtime.h>
#include <math.h>

#define NN 100000
#define NE 1600000
#define NG 64
#define FF 50
#define NL 3
#define NBUCK ((NN + 255) / 256)   // 391
#define CAP 8192                   // per-bucket segment capacity (expected 4096 +/- 64)

typedef short bf16x8 __attribute__((ext_vector_type(8)));
typedef float f32x4 __attribute__((ext_vector_type(4)));

__device__ __forceinline__ short f2bf(float f) {
  return __builtin_bit_cast(short, (__bf16)f);
}
__device__ __forceinline__ float bf2f(short s) {
  unsigned int u = ((unsigned int)(unsigned short)s) << 16;
  return __builtin_bit_cast(float, u);
}
__device__ __forceinline__ float2 unpk2(unsigned u) {
  float2 v;
  v.x = __builtin_bit_cast(float, u << 16);
  v.y = __builtin_bit_cast(float, u & 0xFFFF0000u);
  return v;
}
__device__ __forceinline__ unsigned pk2(float2 v) {
  return (unsigned)(unsigned short)f2bf(v.x) | ((unsigned)(unsigned short)f2bf(v.y) << 16);
}

// load a 16B bf16 fragment and apply BN+ReLU per element (ab = per-feature a,b)
__device__ __forceinline__ bf16x8 ldfrag_bn(const short* base, const float2* __restrict__ ab, int kbase) {
  bf16x8 raw = *(const bf16x8*)base;
  unsigned u[4];
  __builtin_memcpy(u, &raw, 16);
  short t[8] __attribute__((aligned(16)));
#pragma unroll
  for (int i = 0; i < 4; ++i) {
    float2 v = unpk2(u[i]);
    float2 a0 = ab[kbase + 2 * i], a1 = ab[kbase + 2 * i + 1];
    v.x = fmaxf(fmaf(v.x, a0.x, a0.y), 0.f);
    v.y = fmaxf(fmaf(v.y, a1.x, a1.y), 0.f);
    ((unsigned*)t)[i] = pk2(v);
  }
  bf16x8 r;
  __builtin_memcpy(&r, t, 16);
  return r;
}

// ---------------- phase A: bin edges into per-bucket segments ----------------
__global__ __launch_bounds__(256) void k_bucket2(const int* __restrict__ src, const int* __restrict__ dst,
                                                 int* __restrict__ bcnt, unsigned* __restrict__ tmp) {
  __shared__ int hist[NBUCK];
  __shared__ int base[NBUCK];
  int t = threadIdx.x;
  for (int i = t; i < NBUCK; i += 256) hist[i] = 0;
  __syncthreads();
  int e0 = blockIdx.x * 4096;
  int myb[16], myrank[16];
  unsigned mypack[16];
#pragma unroll
  for (int i = 0; i < 16; ++i) {
    int e = e0 + i * 256 + t;
    if (e < NE) {
      int s = src[e], d = dst[e];
      int b = d >> 8;
      myb[i] = b;
      mypack[i] = ((unsigned)(d & 255) << 17) | (unsigned)s;
      myrank[i] = atomicAdd(&hist[b], 1);
    } else myb[i] = -1;
  }
  __syncthreads();
  for (int i = t; i < NBUCK; i += 256)
    base[i] = hist[i] ? atomicAdd(&bcnt[i], hist[i]) : 0;
  __syncthreads();
#pragma unroll
  for (int i = 0; i < 16; ++i)
    if (myb[i] >= 0) {
      int pos = base[myb[i]] + myrank[i];
      if (pos < CAP) tmp[(size_t)myb[i] * CAP + pos] = mypack[i];
    }
}

// ---------------- bucket-count prefix (one block) ----------------
__global__ void k_bscan(const int* __restrict__ bcnt, int* __restrict__ bbase, int* __restrict__ off) {
  __shared__ int sm[512];
  int t = threadIdx.x;
  int v = (t < NBUCK) ? bcnt[t] : 0;
  sm[t] = v;
  __syncthreads();
  for (int o = 1; o < 512; o <<= 1) {
    int u = (t >= o) ? sm[t - o] : 0;
    __syncthreads();
    sm[t] += u;
    __syncthreads();
  }
  if (t < NBUCK) bbase[t] = sm[t] - v;
  if (t == 0) off[NN] = NE;
}

// ---------------- phase B: bucket segment -> CSR + degrees/offsets/node-init ----------------
__global__ __launch_bounds__(256) void k_bsort2(const unsigned* __restrict__ tmp, const int* __restrict__ bcnt,
                                                const int* __restrict__ bbase, int* __restrict__ off,
                                                int* __restrict__ ssrc, float* __restrict__ dinv,
                                                float* __restrict__ lgc, float* __restrict__ scal) {
  __shared__ unsigned seg[CAP];    // 32 KB
  __shared__ int loc[256];
  __shared__ int wred[4];
  __shared__ float fred[4];
  int b = blockIdx.x, t = threadIdx.x;
  int c = bcnt[b];
  if (c > CAP) c = CAP;
  int base = bbase[b];
  const unsigned* sp = tmp + (size_t)b * CAP;
  loc[t] = 0;
  __syncthreads();
  // pass 1: stage segment in LDS + count per-node degree
  for (int e = t; e < c; e += 256) {
    unsigned p = sp[e];
    seg[e] = p;
    atomicAdd(&loc[p >> 17], 1);
  }
  __syncthreads();
  int d = loc[t];                      // degree of node b*256+t (0 for n>=NN)
  int lane = t & 63, w = t >> 6;
  // inclusive wave scan of degrees
  int v = d;
#pragma unroll
  for (int o = 1; o < 64; o <<= 1) {
    int u = __shfl_up(v, o);
    if (lane >= o) v += u;
  }
  if (lane == 63) wred[w] = v;
  // scal partial (sum of log1p(deg_raw))
  int n = b * 256 + t;
  float lp = (n < NN) ? log1pf((float)d) : 0.f;
#pragma unroll
  for (int o = 32; o > 0; o >>= 1) lp += __shfl_down(lp, o);
  if (lane == 0) fred[w] = lp;
  __syncthreads();
  int excl = v - d;
#pragma unroll
  for (int i = 0; i < 4; ++i)
    if (i < w) excl += wred[i];
  if (t == 0) atomicAdd(scal, fred[0] + fred[1] + fred[2] + fred[3]);
  if (n < NN) {
    off[n] = base + excl;
    dinv[n] = rsqrtf((float)(d + 1));
    lgc[n] = log1pf((float)(d > 1 ? d : 1));
  }
  loc[t] = base + excl;                // own-slot overwrite; only thread t read loc[t]
  __syncthreads();
  // pass 2: scatter to final CSR positions
  for (int e = t; e < c; e += 256) {
    unsigned p = seg[e];
    int pos = atomicAdd(&loc[p >> 17], 1);
    ssrc[pos] = (int)(p & 0x1FFFFu);
  }
}

// ---------------- fuse post_W @ lin_W ----------------
__global__ void k_fusew(const float* __restrict__ postW, const float* __restrict__ postb,
                        const float* __restrict__ linW, const float* __restrict__ linb,
                        float* __restrict__ A, float* __restrict__ bias2) {
  int wid = (blockIdx.x * blockDim.x + threadIdx.x) >> 6;
  int f = threadIdx.x & 63;
  if (wid >= 3 * 651) return;
  int l = wid / 651, r = wid % 651;
  int fc = f < FF ? f : FF - 1;
  const float* lw = linW + l * FF * FF;
  float acc = 0.f;
  if (r < 650) {
    const float* pw = postW + (l * 650 + r) * FF;
    for (int j = 0; j < FF; ++j) acc += pw[j] * lw[j * FF + fc];
    if (f < FF) A[(l * 650 + r) * FF + f] = acc;
  } else {
    const float* pb = postb + l * FF;
    for (int j = 0; j < FF; ++j) acc += pb[j] * lw[j * FF + fc];
    bias2[l * 64 + f] = (f < FF) ? (acc + linb[l * FF + f]) : 0.f;
  }
}

// ---------------- pack A ----------------
__global__ void k_packA(const float* __restrict__ Af, short* __restrict__ Abt) {
  int t = blockIdx.x * 256 + threadIdx.x;
  if (t >= 3 * 13 * 64 * 64) return;
  int kk = t & 63;
  int f = (t >> 6) & 63;
  int lc = t >> 12;
  int c = lc % 13;
  int l = lc / 13;
  float v = 0.f;
  if (kk < FF && f < FF) v = Af[((size_t)(l * 650 + c * FF + kk)) * FF + f];
  Abt[t] = f2bf(v);
}

// ---------------- pack pre_W ----------------
__global__ void k_packP(const float* __restrict__ preW, short* __restrict__ Pbt) {
  int t = blockIdx.x * 256 + threadIdx.x;
  if (t >= NL * 2 * 64 * 64) return;
  int kk = t & 63;
  int f = (t >> 6) & 63;
  int ls = t >> 12;
  int s = ls & 1, l = ls >> 1;
  float v = 0.f;
  if (kk < FF && f < FF) v = preW[(size_t)(l * 100 + s * FF + kk) * FF + f];
  Pbt[t] = f2bf(v);
}

// ---------------- GCN pre (writes split half-feature arrays) ----------------
__global__ void k_gcnpre(const float* __restrict__ x, const float* __restrict__ Wg,
                         const float* __restrict__ dinv, short* __restrict__ pA,
                         short* __restrict__ pB) {
  int t = blockIdx.x * 256 + threadIdx.x;
  int n = t >> 6, f = t & 63;
  if (n >= NN) return;
  float v = 0.f;
  if (f < FF) v = (x[2 * n] * Wg[f] + x[2 * n + 1] * Wg[FF + f]) * dinv[n];
  short* dst = (f < 32) ? pA : pB;
  dst[(n << 5) + (f & 31)] = f2bf(v);
}

// ---------------- GCN aggregation: split-array two-phase gather ----------------
// Round-6 change: 3 different inner loops all pinned at ~61-64us with FETCH
// 93MB @ ~2.4TB/s L2-miss traffic -> byte-bound, not instruction-bound.
// Split p into two [NN][32] arrays (6.4MB each, 64B rows = 1 cache line) and
// gather in two sequential phases: active working set halves -> L2-resident
// fraction rises -> fewer miss bytes. Half-wave = one edge of a pair.
__global__ void k_gcnagg(const short* __restrict__ pA, const short* __restrict__ pB,
                         const int* __restrict__ off, const int* __restrict__ ssrc,
                         const float* __restrict__ dinv, const float* __restrict__ bg,
                         short* __restrict__ hb) {
  int wid = (blockIdx.x * blockDim.x + threadIdx.x) >> 6;
  int lane = threadIdx.x & 63;
  if (wid >= NN) return;               // never taken: grid*4 == NN exactly
  int n = wid;
  int hf = lane >> 5, fi = lane & 31;
  int lo = off[n], hi = off[n + 1];
  float dv = dinv[n];
#pragma unroll 1
  for (int ph = 0; ph < 2; ++ph) {
    const short* P = ph ? pB : pA;
    float acc = (hf == 0) ? bf2f(P[(n << 5) + fi]) : 0.f;   // self term once
    for (int base = lo; base < hi; base += 64) {
      int rem = hi - base;
      int cnt = rem > 64 ? 64 : rem;
      int sidx = (base + lane < hi) ? ssrc[base + lane] : 0;
      int k = 0;
      for (; k + 16 <= cnt; k += 16) {   // 8 pairs = 16 edges in flight
        float v[8];
#pragma unroll
        for (int i = 0; i < 8; ++i) {
          int sA = __builtin_amdgcn_readlane(sidx, k + 2 * i);
          int sB = __builtin_amdgcn_readlane(sidx, k + 2 * i + 1);
          int s = hf ? sB : sA;
          v[i] = bf2f(P[(s << 5) + fi]);
        }
#pragma unroll
        for (int i = 0; i < 8; ++i) acc += v[i];
      }
      for (; k + 2 <= cnt; k += 2) {
        int sA = __builtin_amdgcn_readlane(sidx, k);
        int sB = __builtin_amdgcn_readlane(sidx, k + 1);
        int s = hf ? sB : sA;
        acc += bf2f(P[(s << 5) + fi]);
      }
      if (k < cnt) {                     // odd last edge -> half 0 only
        int sA = __builtin_amdgcn_readlane(sidx, cnt - 1);
        if (hf == 0) acc += bf2f(P[(sA << 5) + fi]);
      }
    }
    acc += __shfl_xor(acc, 32);
    if (lane < 32) {
      int col = (ph << 5) + fi;
      float o = (col < FF) ? (dv * acc + bg[col]) : 0.f;
      hb[(size_t)n * 64 + col] = f2bf(o);
    }
    if (ph == 0) __syncthreads();        // align phases across the block
  }
}

// ---------------- PNA pre (MFMA; bbh now split into bA/bB halves) ----------------
__global__ __launch_bounds__(256) void k_preM(const short* __restrict__ hin, const float2* __restrict__ ab,
                                              const short* __restrict__ Pbt, const float* __restrict__ preb,
                                              short* __restrict__ cbh, short* __restrict__ bbA,
                                              short* __restrict__ bbB, int l) {
  int tid = threadIdx.x;
  int w = tid >> 6, lane = tid & 63;
  int q = lane >> 4, m16 = lane & 15;
  int n0 = blockIdx.x * 64 + w * 16;
  int anode = n0 + m16;
  int nsafe = anode < NN ? anode : 0;
  bf16x8 afr[2];
#pragma unroll
  for (int hh = 0; hh < 2; ++hh) {
    const short* srcp = hin + (size_t)nsafe * 64 + hh * 32 + q * 8;
    afr[hh] = ab ? ldfrag_bn(srcp, ab, hh * 32 + q * 8) : *(const bf16x8*)srcp;
  }
  const short* P0 = Pbt + l * 8192;
  f32x4 aT[4], aB2[4];
#pragma unroll
  for (int ft = 0; ft < 4; ++ft) {
    aT[ft] = (f32x4){0.f, 0.f, 0.f, 0.f};
    aB2[ft] = (f32x4){0.f, 0.f, 0.f, 0.f};
  }
#pragma unroll
  for (int hh = 0; hh < 2; ++hh) {
#pragma unroll
    for (int ft = 0; ft < 4; ++ft) {
      bf16x8 b0 = *(const bf16x8*)(P0 + ((ft * 16 + m16) << 6) + hh * 32 + q * 8);
      bf16x8 b1 = *(const bf16x8*)(P0 + 4096 + ((ft * 16 + m16) << 6) + hh * 32 + q * 8);
      aT[ft] = __builtin_amdgcn_mfma_f32_16x16x32_bf16(afr[hh], b0, aT[ft], 0, 0, 0);
      aB2[ft] = __builtin_amdgcn_mfma_f32_16x16x32_bf16(afr[hh], b1, aB2[ft], 0, 0, 0);
    }
  }
#pragma unroll
  for (int r = 0; r < 4; ++r) {
    int node = n0 + q * 4 + r;
    if (node >= NN) continue;
#pragma unroll
    for (int ft = 0; ft < 4; ++ft) {
      int col = ft * 16 + m16;
      cbh[node * 64 + col] = (col < FF) ? f2bf(aT[ft][r] + preb[l * FF + col]) : 0;
      short* dst = (ft < 2) ? bbA : bbB;      // col<32 iff ft<2
      dst[(node << 5) + (col & 31)] = f2bf(aB2[ft][r]);
    }
  }
}

// ---------------- PNA aggregation: split-array two-phase gather ----------------
__global__ void k_agg(const short* __restrict__ bbA, const short* __restrict__ bbB,
                      const short* __restrict__ cbh,
                      const int* __restrict__ off, const int* __restrict__ ssrc,
                      const float* __restrict__ lgc, const float* __restrict__ scal,
                      short* __restrict__ agb, float* __restrict__ ampatt) {
  int wid = (blockIdx.x * blockDim.x + threadIdx.x) >> 6;
  int lane = threadIdx.x & 63;
  if (wid >= NN) return;               // never taken: grid*4 == NN exactly
  int n = wid;
  int hf = lane >> 5, fi = lane & 31;
  int lo = off[n], hi = off[n + 1];
  int d = hi - lo;
  short* row = agb + (size_t)n * 256;
#pragma unroll 1
  for (int ph = 0; ph < 2; ++ph) {
    const short* B = ph ? bbB : bbA;
    float S = 0.f, S2 = 0.f, MN = INFINITY, MX = -INFINITY;
    for (int base = lo; base < hi; base += 64) {
      int rem = hi - base;
      int cnt = rem > 64 ? 64 : rem;
      int sidx = (base + lane < hi) ? ssrc[base + lane] : 0;
      int k = 0;
      for (; k + 16 <= cnt; k += 16) {   // 8 pairs = 16 edges in flight
        float v[8];
#pragma unroll
        for (int i = 0; i < 8; ++i) {
          int sA = __builtin_amdgcn_readlane(sidx, k + 2 * i);
          int sB = __builtin_amdgcn_readlane(sidx, k + 2 * i + 1);
          int s = hf ? sB : sA;
          v[i] = bf2f(B[(s << 5) + fi]);
        }
#pragma unroll
        for (int i = 0; i < 8; ++i) {
          float x = v[i];
          S += x; S2 = fmaf(x, x, S2);
          MN = fminf(MN, x); MX = fmaxf(MX, x);
        }
      }
      for (; k + 2 <= cnt; k += 2) {
        int sA = __builtin_amdgcn_readlane(sidx, k);
        int sB = __builtin_amdgcn_readlane(sidx, k + 1);
        int s = hf ? sB : sA;
        float x = bf2f(B[(s << 5) + fi]);
        S += x; S2 = fmaf(x, x, S2);
        MN = fminf(MN, x); MX = fmaxf(MX, x);
      }
      if (k < cnt) {                     // odd last edge -> half 0 only
        int sA = __builtin_amdgcn_readlane(sidx, cnt - 1);
        if (hf == 0) {
          float x = bf2f(B[(sA << 5) + fi]);
          S += x; S2 = fmaf(x, x, S2);
          MN = fminf(MN, x); MX = fmaxf(MX, x);
        }
      }
    }
    S += __shfl_xor(S, 32); S2 += __shfl_xor(S2, 32);
    MN = fminf(MN, __shfl_xor(MN, 32)); MX = fmaxf(MX, __shfl_xor(MX, 32));
    if (lane < 32) {
      int col = (ph << 5) + fi;
      bool valid = col < FF;
      float mean, mnv, mxv, stdv;
      if (d > 0) {
        float inv = 1.f / (float)d;
        float m = S * inv;
        float vv = S2 * inv - m * m; vv = vv > 0.f ? vv : 0.f;
        stdv = sqrtf(vv + 1e-5f);
        float c = valid ? bf2f(cbh[(size_t)n * 64 + col]) : 0.f;
        mean = c + m;
        mnv = c + MN;
        mxv = c + MX;
      } else {
        mean = mnv = mxv = 0.f;
        stdv = sqrtf(1e-5f);
      }
      row[col]       = valid ? f2bf(mean) : 0;
      row[64 + col]  = valid ? f2bf(mnv) : 0;
      row[128 + col] = valid ? f2bf(mxv) : 0;
      row[192 + col] = valid ? f2bf(stdv) : 0;
    }
    if (ph == 0) __syncthreads();        // align phases across the block
  }
  if (lane == 0) {
    float avg = scal[0] * (1.f / NN);
    float lg = lgc[n];
    ampatt[2 * n] = lg / avg;
    ampatt[2 * n + 1] = avg / lg;
  }
}

// ---------------- post GEMM: 128 nodes/block, 512 threads (8 waves), one-round residency ----------------
__global__ __launch_bounds__(512, 2) void k_gemm(const short* __restrict__ h, const float2* __restrict__ ab,
                                                 const short* __restrict__ agb, const float* __restrict__ ampatt,
                                                 const short* __restrict__ Abt, const float* __restrict__ bias2,
                                                 short* __restrict__ hout, float* __restrict__ bnsumR) {
  __shared__ short Bs[3][64][72];   // 27.6 KB
  int tid = threadIdx.x;
  int w = tid >> 6, lane = tid & 63;
  int q = lane >> 4, m16 = lane & 15;
  int n0 = blockIdx.x * 128 + w * 16;

  // A-fragments in registers
  int anode = n0 + m16;
  int nsafe = anode < NN ? anode : 0;
  bf16x8 afr[5][2];
  {
#pragma unroll
    for (int hh = 0; hh < 2; ++hh) {
      const short* srcp = h + (size_t)nsafe * 64 + hh * 32 + q * 8;
      afr[0][hh] = ab ? ldfrag_bn(srcp, ab, hh * 32 + q * 8) : *(const bf16x8*)srcp;
    }
    const short* arow = agb + (size_t)nsafe * 256;
#pragma unroll
    for (int c = 1; c <= 4; ++c)
#pragma unroll
      for (int hh = 0; hh < 2; ++hh)
        afr[c][hh] = *(const bf16x8*)(arow + (c - 1) * 64 + hh * 32 + q * 8);
  }

  f32x4 acc[3][4];
#pragma unroll
  for (int s = 0; s < 3; ++s)
#pragma unroll
    for (int ft = 0; ft < 4; ++ft) acc[s][ft] = (f32x4){0.f, 0.f, 0.f, 0.f};

  // B staging roles: first 4 waves only
  bool stager = tid < 256;
  int bf = tid >> 2;            // 0..63 for stagers
  int bko = (tid & 3) * 16;
  float4 rg[3][2];
  if (stager) {
    const float4* g = (const float4*)(Abt + (bf << 6) + bko);
    rg[0][0] = g[0]; rg[0][1] = g[1];
  }
  for (int ph = 0; ph < 5; ++ph) {
    int nslice = (ph == 0) ? 1 : 3;
    if (ph) __syncthreads();
    if (stager) {
      for (int s = 0; s < nslice; ++s) {
        *(float4*)&Bs[s][bf][bko] = rg[s][0];
        *(float4*)&Bs[s][bf][bko + 8] = rg[s][1];
      }
    }
    __syncthreads();
    if (stager && ph < 4) {
#pragma unroll
      for (int s = 0; s < 3; ++s) {
        int chunk = (ph + 1) + 4 * s;
        const float4* g = (const float4*)(Abt + (chunk << 12) + (bf << 6) + bko);
        rg[s][0] = g[0]; rg[s][1] = g[1];
      }
    }
    if (ph == 0) {
#pragma unroll
      for (int hh = 0; hh < 2; ++hh)
#pragma unroll
        for (int ft = 0; ft < 4; ++ft) {
          bf16x8 b = *(const bf16x8*)&Bs[0][ft * 16 + m16][hh * 32 + q * 8];
          acc[0][ft] = __builtin_amdgcn_mfma_f32_16x16x32_bf16(afr[0][hh], b, acc[0][ft], 0, 0, 0);
        }
    } else {
#pragma unroll
      for (int hh = 0; hh < 2; ++hh)
#pragma unroll
        for (int s = 0; s < 3; ++s)
#pragma unroll
          for (int ft = 0; ft < 4; ++ft) {
            bf16x8 b = *(const bf16x8*)&Bs[s][ft * 16 + m16][hh * 32 + q * 8];
            acc[s][ft] = __builtin_amdgcn_mfma_f32_16x16x32_bf16(afr[ph][hh], b, acc[s][ft], 0, 0, 0);
          }
    }
  }

  // epilogue: bf16 store (pad cols zeroed) + BN partials in fp32
  float sacc[4] = {0.f, 0.f, 0.f, 0.f};
  float qacc[4] = {0.f, 0.f, 0.f, 0.f};
#pragma unroll
  for (int r = 0; r < 4; ++r) {
    int node = n0 + q * 4 + r;
    if (node >= NN) continue;
    float2 aa = *(const float2*)(ampatt + 2 * node);
#pragma unroll
    for (int ft = 0; ft < 4; ++ft) {
      int col = ft * 16 + m16;
      float val = 0.f;
      if (col < FF) {
        val = acc[0][ft][r] + aa.x * acc[1][ft][r] + aa.y * acc[2][ft][r] + bias2[col];
        sacc[ft] += val;
        qacc[ft] = fmaf(val, val, qacc[ft]);
      }
      hout[node * 64 + col] = f2bf(val);
    }
  }
  // per-wave reduce: lanes sharing m16 (differ in bits 4,5) sum their 4 nodes
#pragma unroll
  for (int ft = 0; ft < 4; ++ft) {
    sacc[ft] += __shfl_xor(sacc[ft], 16);
    sacc[ft] += __shfl_xor(sacc[ft], 32);
    qacc[ft] += __shfl_xor(qacc[ft], 16);
    qacc[ft] += __shfl_xor(qacc[ft], 32);
  }
  // block-level reduce in LDS (Bs is dead after last MFMA phase), then 2
  // atomic wave-instructions per block.
  __syncthreads();                       // all waves done reading Bs
  float* red = (float*)&Bs[0][0][0];     // 8 waves x 128 floats = 4 KB
  if (lane < 16) {
#pragma unroll
    for (int ft = 0; ft < 4; ++ft) {
      red[w * 128 + ft * 16 + lane]      = sacc[ft];
      red[w * 128 + 64 + ft * 16 + lane] = qacc[ft];
    }
  }
  __syncthreads();
  if (tid < 128) {
    float v = 0.f;
#pragma unroll
    for (int i = 0; i < 8; ++i) v += red[i * 128 + tid];
    atomicAdd(&bnsumR[(blockIdx.x & 7) * 128 + tid], v);
  }
}

// ---------------- BN coeffs from 8 replicas ----------------
__global__ void k_bnab(const float* __restrict__ bnsumR, const float* __restrict__ gamma,
                       const float* __restrict__ beta, float2* __restrict__ ab, int l) {
  int f = threadIdx.x;
  float a = 0.f, b = 0.f;
  if (f < FF) {
    float s = 0.f, q = 0.f;
    for (int r = 0; r < 8; ++r) { s += bnsumR[r * 128 + f]; q += bnsumR[r * 128 + 64 + f]; }
    float mu = s * (1.f / NN);
    float vq = q * (1.f / NN) - mu * mu;
    float rs = rsqrtf((vq > 0.f ? vq : 0.f) + 1e-5f);
    a = rs * gamma[l * FF + f];
    b = beta[l * FF + f] - mu * a;
  }
  ab[f] = make_float2(a, b);
}

// ---------------- graph partial sums (fused BN+ReLU of last layer, bf16 h) ----------------
__global__ void k_gsum(const short* __restrict__ h, const float2* __restrict__ ab,
                       const int* __restrict__ batch, float* __restrict__ gsum) {
  int w = threadIdx.x >> 6, lane = threadIdx.x & 63;
  int fc = lane < FF ? lane : FF - 1;
  bool act = lane < FF;
  float2 p = ab[fc];
  int n0 = blockIdx.x * 256 + w * 64;
  if (n0 >= NN) return;
  int nEnd = n0 + 64 < NN ? n0 + 64 : NN;
  float acc = 0.f;
  int gcur = batch[n0];
  for (int n = n0; n < nEnd; ++n) {
    int g = batch[n];
    if (g != gcur) {
      if (act) atomicAdd(&gsum[gcur * 64 + lane], acc);
      acc = 0.f; gcur = g;
    }
    float v = bf2f(h[n * 64 + fc]);
    acc += fmaxf(fmaf(v, p.x, p.y), 0.f);
  }
  if (act) atomicAdd(&gsum[gcur * 64 + lane], acc);
}

// ---------------- final MLP ----------------
__global__ void k_mlp(const float* __restrict__ gsum, const float* __restrict__ W1,
                      const float* __restrict__ b1, const float* __restrict__ W2,
                      const float* __restrict__ b2, float* __restrict__ out) {
  int g = threadIdx.x;
  if (g >= NG) return;
  float gv[FF];
#pragma unroll
  for (int f = 0; f < FF; ++f) gv[f] = gsum[g * 64 + f];
  float r = b2[0];
  for (int j = 0; j < 25; ++j) {
    float a = b1[j];
#pragma unroll
    for (int f = 0; f < FF; ++f) a = fmaf(gv[f], W1[f * 25 + j], a);
    r += fmaxf(a, 0.f) * W2[j];
  }
  out[g] = r;
}

extern "C" void kernel_launch(void* const* d_in, const int* in_sizes, int n_in,
                              void* d_out, int out_size, void* d_ws, size_t ws_size,
                              hipStream_t stream) {
  const float* x     = (const float*)d_in[0];
  const int*   ei    = (const int*)d_in[1];
  const int*   src   = ei;
  const int*   dst   = ei + NE;
  const int*   batch = (const int*)d_in[2];
  const float* Wg    = (const float*)d_in[3];
  const float* bg    = (const float*)d_in[4];
  const float* preW  = (const float*)d_in[5];
  const float* preb  = (const float*)d_in[6];
  const float* postW = (const float*)d_in[7];
  const float* postb = (const float*)d_in[8];
  const float* linW  = (const float*)d_in[9];
  const float* linb  = (const float*)d_in[10];
  const float* gamma = (const float*)d_in[11];
  const float* beta  = (const float*)d_in[12];
  const float* W1    = (const float*)d_in[13];
  const float* b1    = (const float*)d_in[14];
  const float* W2    = (const float*)d_in[15];
  const float* b2    = (const float*)d_in[16];
  float* out = (float*)d_out;

  char* W = (char*)d_ws;
  int*    bcnt   = (int*)(W + 0);            // 2048 (391 used)
  int*    bbase  = (int*)(W + 2048);         // 2048
  int*    off    = (int*)(W + 400384);       // 400896
  float*  dinv   = (float*)(W + 807424);     // 400384
  float*  lgc    = (float*)(W + 1207808);    // 400384
  float*  scal   = (float*)(W + 1608192);    // 512
  float*  bnsum  = (float*)(W + 1608704);    // 12288
  float2* ab     = (float2*)(W + 1620992);   // 1536
  float*  Af     = (float*)(W + 1622528);    // 390144
  float*  bias2  = (float*)(W + 2012672);    // 1024
  short*  Abt    = (short*)(W + 2013696);    // 319488
  short*  Pbt    = (short*)(W + 2333184);    // 49152
  int*    ssrc   = (int*)(W + 8782336);      // 6400000
  short*  hA     = (short*)(W + 15182336);   // 12800256 (bf16 [node][64])
  short*  hB     = (short*)(W + 27982592);   // 12800256
  short*  cbh    = (short*)(W + 40782848);   // 12800256 (bf16 [node][64])
  short*  bbh    = (short*)(W + 53583104);   // 12800256 (split: A=[NN][32], B=[NN][32]; also GCN p)
  short*  agb    = (short*)(W + 66383360);   // 51200256 (bf16 [node][256])
  float*  ampatt = (float*)(W + 117583616);  // 800256
  float*  gsum   = (float*)(W + 118383872);  // 16384   (total ~118.4 MB)
  // split halves of the gather array (6.4MB each, 64B rows = 1 cache line)
  short*  bbA    = bbh;
  short*  bbB    = bbh + (size_t)NN * 32;
  // tmp (bucket segments, 391*8192*4 = 12.8 MB) aliases the agb region:
  // its lifetime (k_bucket2 -> k_bsort2) ends before k_agg first writes agb,
  // and k_agg fully rewrites every agb row each layer (stream-ordered).
  unsigned* tmp  = (unsigned*)agb;

  hipMemsetAsync(bcnt, 0, 2048, stream);
  hipMemsetAsync(scal, 0, 12800, stream);   // scal + bnsum
  hipMemsetAsync(gsum, 0, 16384, stream);

  k_bucket2<<<(NE + 4095) / 4096, 256, 0, stream>>>(src, dst, bcnt, tmp);
  k_bscan<<<1, 512, 0, stream>>>(bcnt, bbase, off);
  k_bsort2<<<NBUCK, 256, 0, stream>>>(tmp, bcnt, bbase, off, ssrc, dinv, lgc, scal);
  k_fusew<<<(3 * 651 + 3) / 4, 256, 0, stream>>>(postW, postb, linW, linb, Af, bias2);
  k_packA<<<(3 * 13 * 64 * 64 + 255) / 256, 256, 0, stream>>>(Af, Abt);
  k_packP<<<(NL * 2 * 64 * 64 + 255) / 256, 256, 0, stream>>>(preW, Pbt);

  k_gcnpre<<<NN / 4, 256, 0, stream>>>(x, Wg, dinv, bbA, bbB);
  k_gcnagg<<<NN / 4, 256, 0, stream>>>(bbA, bbB, off, ssrc, dinv, bg, hA);

  short* hin = hA;
  short* hout = hB;
  for (int l = 0; l < NL; ++l) {
    const float2* abl = (l == 0) ? nullptr : (ab + (l - 1) * 64);
    k_preM<<<(NN + 63) / 64, 256, 0, stream>>>(hin, abl, Pbt, preb, cbh, bbA, bbB, l);
    k_agg<<<NN / 4, 256, 0, stream>>>(bbA, bbB, cbh, off, ssrc, lgc, scal, agb, ampatt);
    k_gemm<<<(NN + 127) / 128, 512, 0, stream>>>(hin, abl, agb, ampatt,
                                                 Abt + l * 13 * 4096, bias2 + l * 64, hout,
                                                 bnsum + l * 1024);
    k_bnab<<<1, 64, 0, stream>>>(bnsum + l * 1024, gamma, beta, ab + l * 64, l);
    short* t = hin; hin = hout; hout = t;
  }
  k_gsum<<<NBUCK, 256, 0, stream>>>(hin, ab + 2 * 64, batch, gsum);
  k_mlp<<<1, 64, 0, stream>>>(gsum, W1, b1, W2, b2, out);
}

// Round 8
// 653.412 us; speedup vs baseline: 1.3199x; 1.3199x over previous
//
#include <hip/hip_runtime.h>
#include <math.h>

#define NN 100000
#define NE 1600000
#define NG 64
#define FF 50
#define NL 3
#define NBUCK ((NN + 255) / 256)   // 391
#define CAP 8192                   // per-bucket segment capacity (expected 4096 +/- 64)

typedef short bf16x8 __attribute__((ext_vector_type(8)));
typedef float f32x4 __attribute__((ext_vector_type(4)));

__device__ __forceinline__ short f2bf(float f) {
  return __builtin_bit_cast(short, (__bf16)f);
}
__device__ __forceinline__ float bf2f(short s) {
  unsigned int u = ((unsigned int)(unsigned short)s) << 16;
  return __builtin_bit_cast(float, u);
}
__device__ __forceinline__ float2 unpk2(unsigned u) {
  float2 v;
  v.x = __builtin_bit_cast(float, u << 16);
  v.y = __builtin_bit_cast(float, u & 0xFFFF0000u);
  return v;
}
__device__ __forceinline__ unsigned pk2(float2 v) {
  return (unsigned)(unsigned short)f2bf(v.x) | ((unsigned)(unsigned short)f2bf(v.y) << 16);
}

// load a 16B bf16 fragment and apply BN+ReLU per element (ab = per-feature a,b)
__device__ __forceinline__ bf16x8 ldfrag_bn(const short* base, const float2* __restrict__ ab, int kbase) {
  bf16x8 raw = *(const bf16x8*)base;
  unsigned u[4];
  __builtin_memcpy(u, &raw, 16);
  short t[8] __attribute__((aligned(16)));
#pragma unroll
  for (int i = 0; i < 4; ++i) {
    float2 v = unpk2(u[i]);
    float2 a0 = ab[kbase + 2 * i], a1 = ab[kbase + 2 * i + 1];
    v.x = fmaxf(fmaf(v.x, a0.x, a0.y), 0.f);
    v.y = fmaxf(fmaf(v.y, a1.x, a1.y), 0.f);
    ((unsigned*)t)[i] = pk2(v);
  }
  bf16x8 r;
  __builtin_memcpy(&r, t, 16);
  return r;
}

// ---------------- phase A: bin edges into per-bucket segments ----------------
__global__ __launch_bounds__(256) void k_bucket2(const int* __restrict__ src, const int* __restrict__ dst,
                                                 int* __restrict__ bcnt, unsigned* __restrict__ tmp) {
  __shared__ int hist[NBUCK];
  __shared__ int base[NBUCK];
  int t = threadIdx.x;
  for (int i = t; i < NBUCK; i += 256) hist[i] = 0;
  __syncthreads();
  int e0 = blockIdx.x * 4096;
  int myb[16], myrank[16];
  unsigned mypack[16];
#pragma unroll
  for (int i = 0; i < 16; ++i) {
    int e = e0 + i * 256 + t;
    if (e < NE) {
      int s = src[e], d = dst[e];
      int b = d >> 8;
      myb[i] = b;
      mypack[i] = ((unsigned)(d & 255) << 17) | (unsigned)s;
      myrank[i] = atomicAdd(&hist[b], 1);
    } else myb[i] = -1;
  }
  __syncthreads();
  for (int i = t; i < NBUCK; i += 256)
    base[i] = hist[i] ? atomicAdd(&bcnt[i], hist[i]) : 0;
  __syncthreads();
#pragma unroll
  for (int i = 0; i < 16; ++i)
    if (myb[i] >= 0) {
      int pos = base[myb[i]] + myrank[i];
      if (pos < CAP) tmp[(size_t)myb[i] * CAP + pos] = mypack[i];
    }
}

// ---------------- bucket-count prefix (one block) ----------------
__global__ void k_bscan(const int* __restrict__ bcnt, int* __restrict__ bbase, int* __restrict__ off) {
  __shared__ int sm[512];
  int t = threadIdx.x;
  int v = (t < NBUCK) ? bcnt[t] : 0;
  sm[t] = v;
  __syncthreads();
  for (int o = 1; o < 512; o <<= 1) {
    int u = (t >= o) ? sm[t - o] : 0;
    __syncthreads();
    sm[t] += u;
    __syncthreads();
  }
  if (t < NBUCK) bbase[t] = sm[t] - v;
  if (t == 0) off[NN] = NE;
}

// ---------------- phase B: bucket segment -> CSR + degrees/offsets/node-init ----------------
__global__ __launch_bounds__(256) void k_bsort2(const unsigned* __restrict__ tmp, const int* __restrict__ bcnt,
                                                const int* __restrict__ bbase, int* __restrict__ off,
                                                int* __restrict__ ssrc, float* __restrict__ dinv,
                                                float* __restrict__ lgc, float* __restrict__ scal) {
  __shared__ unsigned seg[CAP];    // 32 KB
  __shared__ int loc[256];
  __shared__ int wred[4];
  __shared__ float fred[4];
  int b = blockIdx.x, t = threadIdx.x;
  int c = bcnt[b];
  if (c > CAP) c = CAP;
  int base = bbase[b];
  const unsigned* sp = tmp + (size_t)b * CAP;
  loc[t] = 0;
  __syncthreads();
  // pass 1: stage segment in LDS + count per-node degree
  for (int e = t; e < c; e += 256) {
    unsigned p = sp[e];
    seg[e] = p;
    atomicAdd(&loc[p >> 17], 1);
  }
  __syncthreads();
  int d = loc[t];                      // degree of node b*256+t (0 for n>=NN)
  int lane = t & 63, w = t >> 6;
  // inclusive wave scan of degrees
  int v = d;
#pragma unroll
  for (int o = 1; o < 64; o <<= 1) {
    int u = __shfl_up(v, o);
    if (lane >= o) v += u;
  }
  if (lane == 63) wred[w] = v;
  // scal partial (sum of log1p(deg_raw))
  int n = b * 256 + t;
  float lp = (n < NN) ? log1pf((float)d) : 0.f;
#pragma unroll
  for (int o = 32; o > 0; o >>= 1) lp += __shfl_down(lp, o);
  if (lane == 0) fred[w] = lp;
  __syncthreads();
  int excl = v - d;
#pragma unroll
  for (int i = 0; i < 4; ++i)
    if (i < w) excl += wred[i];
  if (t == 0) atomicAdd(scal, fred[0] + fred[1] + fred[2] + fred[3]);
  if (n < NN) {
    off[n] = base + excl;
    dinv[n] = rsqrtf((float)(d + 1));
    lgc[n] = log1pf((float)(d > 1 ? d : 1));
  }
  loc[t] = base + excl;                // own-slot overwrite; only thread t read loc[t]
  __syncthreads();
  // pass 2: scatter to final CSR positions
  for (int e = t; e < c; e += 256) {
    unsigned p = seg[e];
    int pos = atomicAdd(&loc[p >> 17], 1);
    ssrc[pos] = (int)(p & 0x1FFFFu);
  }
}

// ---------------- fuse post_W @ lin_W ----------------
__global__ void k_fusew(const float* __restrict__ postW, const float* __restrict__ postb,
                        const float* __restrict__ linW, const float* __restrict__ linb,
                        float* __restrict__ A, float* __restrict__ bias2) {
  int wid = (blockIdx.x * blockDim.x + threadIdx.x) >> 6;
  int f = threadIdx.x & 63;
  if (wid >= 3 * 651) return;
  int l = wid / 651, r = wid % 651;
  int fc = f < FF ? f : FF - 1;
  const float* lw = linW + l * FF * FF;
  float acc = 0.f;
  if (r < 650) {
    const float* pw = postW + (l * 650 + r) * FF;
    for (int j = 0; j < FF; ++j) acc += pw[j] * lw[j * FF + fc];
    if (f < FF) A[(l * 650 + r) * FF + f] = acc;
  } else {
    const float* pb = postb + l * FF;
    for (int j = 0; j < FF; ++j) acc += pb[j] * lw[j * FF + fc];
    bias2[l * 64 + f] = (f < FF) ? (acc + linb[l * FF + f]) : 0.f;
  }
}

// ---------------- pack A ----------------
__global__ void k_packA(const float* __restrict__ Af, short* __restrict__ Abt) {
  int t = blockIdx.x * 256 + threadIdx.x;
  if (t >= 3 * 13 * 64 * 64) return;
  int kk = t & 63;
  int f = (t >> 6) & 63;
  int lc = t >> 12;
  int c = lc % 13;
  int l = lc / 13;
  float v = 0.f;
  if (kk < FF && f < FF) v = Af[((size_t)(l * 650 + c * FF + kk)) * FF + f];
  Abt[t] = f2bf(v);
}

// ---------------- pack pre_W ----------------
__global__ void k_packP(const float* __restrict__ preW, short* __restrict__ Pbt) {
  int t = blockIdx.x * 256 + threadIdx.x;
  if (t >= NL * 2 * 64 * 64) return;
  int kk = t & 63;
  int f = (t >> 6) & 63;
  int ls = t >> 12;
  int s = ls & 1, l = ls >> 1;
  float v = 0.f;
  if (kk < FF && f < FF) v = preW[(size_t)(l * 100 + s * FF + kk) * FF + f];
  Pbt[t] = f2bf(v);
}

// ---------------- GCN pre ----------------
__global__ void k_gcnpre(const float* __restrict__ x, const float* __restrict__ Wg,
                         const float* __restrict__ dinv, short* __restrict__ pb) {
  int t = blockIdx.x * 256 + threadIdx.x;
  int n = t >> 6, f = t & 63;
  if (n >= NN) return;
  float v = 0.f;
  if (f < FF) v = (x[2 * n] * Wg[f] + x[2 * n + 1] * Wg[FF + f]) * dinv[n];
  pb[n * 64 + f] = f2bf(v);
}

// ---------------- GCN aggregation: scalarized edge walk, 16-deep load pipeline ----------------
// [node][64] bf16 rows = 128B = exactly one L2 line: every miss byte is
// consumed by the fetching wave (round-7 ERRATA: sub-line rows over-fetch 2x).
__global__ void k_gcnagg(const short* __restrict__ pb, const int* __restrict__ off,
                         const int* __restrict__ ssrc, const float* __restrict__ dinv,
                         const float* __restrict__ bg, short* __restrict__ hb) {
  int wid = (blockIdx.x * blockDim.x + threadIdx.x) >> 6;
  int lane = threadIdx.x & 63;
  if (wid >= NN) return;
  int n = wid;
  float acc = bf2f(pb[(size_t)n * 64 + lane]);   // self-loop term (pre-scaled by dinv[n])
  int lo = off[n], hi = off[n + 1];
  for (int base = lo; base < hi; base += 64) {
    int rem = hi - base;
    int cnt = rem > 64 ? 64 : rem;
    int sidx = (base + lane < hi) ? ssrc[base + lane] : 0;
    int k = 0;
    for (; k + 16 <= cnt; k += 16) {
      float v[16];
#pragma unroll
      for (int i = 0; i < 16; ++i) {
        int s = __builtin_amdgcn_readlane(sidx, k + i);
        v[i] = bf2f(pb[(size_t)s * 64 + lane]);
      }
#pragma unroll
      for (int i = 0; i < 16; ++i) acc += v[i];
    }
    if (k < cnt) {
      float v[16];
      int m = cnt - k;                 // 1..15
#pragma unroll
      for (int i = 0; i < 16; ++i) {
        int kk = k + (i < m ? i : 0);  // clamp: duplicates are masked below
        int s = __builtin_amdgcn_readlane(sidx, kk);
        v[i] = bf2f(pb[(size_t)s * 64 + lane]);
      }
#pragma unroll
      for (int i = 0; i < 16; ++i)
        if (i < m) acc += v[i];
    }
  }
  float o = 0.f;
  if (lane < FF) o = dinv[n] * acc + bg[lane];
  hb[(size_t)n * 64 + lane] = f2bf(o);
}

// ---------------- PNA pre (MFMA, LDS-free, bf16 h in, bf16 cb/bb out) ----------------
__global__ __launch_bounds__(256) void k_preM(const short* __restrict__ hin, const float2* __restrict__ ab,
                                              const short* __restrict__ Pbt, const float* __restrict__ preb,
                                              short* __restrict__ cbh, short* __restrict__ bbh, int l) {
  int tid = threadIdx.x;
  int w = tid >> 6, lane = tid & 63;
  int q = lane >> 4, m16 = lane & 15;
  int n0 = blockIdx.x * 64 + w * 16;
  int anode = n0 + m16;
  int nsafe = anode < NN ? anode : 0;
  bf16x8 afr[2];
#pragma unroll
  for (int hh = 0; hh < 2; ++hh) {
    const short* srcp = hin + (size_t)nsafe * 64 + hh * 32 + q * 8;
    afr[hh] = ab ? ldfrag_bn(srcp, ab, hh * 32 + q * 8) : *(const bf16x8*)srcp;
  }
  const short* P0 = Pbt + l * 8192;
  f32x4 aT[4], aB2[4];
#pragma unroll
  for (int ft = 0; ft < 4; ++ft) {
    aT[ft] = (f32x4){0.f, 0.f, 0.f, 0.f};
    aB2[ft] = (f32x4){0.f, 0.f, 0.f, 0.f};
  }
#pragma unroll
  for (int hh = 0; hh < 2; ++hh) {
#pragma unroll
    for (int ft = 0; ft < 4; ++ft) {
      bf16x8 b0 = *(const bf16x8*)(P0 + ((ft * 16 + m16) << 6) + hh * 32 + q * 8);
      bf16x8 b1 = *(const bf16x8*)(P0 + 4096 + ((ft * 16 + m16) << 6) + hh * 32 + q * 8);
      aT[ft] = __builtin_amdgcn_mfma_f32_16x16x32_bf16(afr[hh], b0, aT[ft], 0, 0, 0);
      aB2[ft] = __builtin_amdgcn_mfma_f32_16x16x32_bf16(afr[hh], b1, aB2[ft], 0, 0, 0);
    }
  }
#pragma unroll
  for (int r = 0; r < 4; ++r) {
    int node = n0 + q * 4 + r;
    if (node >= NN) continue;
#pragma unroll
    for (int ft = 0; ft < 4; ++ft) {
      int col = ft * 16 + m16;
      cbh[node * 64 + col] = (col < FF) ? f2bf(aT[ft][r] + preb[l * FF + col]) : 0;
      bbh[node * 64 + col] = f2bf(aB2[ft][r]);
    }
  }
}

// ---------------- PNA aggregation: scalarized edge walk, 16-deep load pipeline ----------------
__global__ void k_agg(const short* __restrict__ bbh, const short* __restrict__ cbh,
                      const int* __restrict__ off, const int* __restrict__ ssrc,
                      const float* __restrict__ lgc, const float* __restrict__ scal,
                      short* __restrict__ agb, float* __restrict__ ampatt) {
  int wid = (blockIdx.x * blockDim.x + threadIdx.x) >> 6;
  int lane = threadIdx.x & 63;
  if (wid >= NN) return;
  int n = wid;
  float S = 0.f, S2 = 0.f;
  float MN = INFINITY, MX = -INFINITY;
  int lo = off[n], hi = off[n + 1];
  for (int base = lo; base < hi; base += 64) {
    int rem = hi - base;
    int cnt = rem > 64 ? 64 : rem;
    int sidx = (base + lane < hi) ? ssrc[base + lane] : 0;
    int k = 0;
    for (; k + 16 <= cnt; k += 16) {
      float v[16];
#pragma unroll
      for (int i = 0; i < 16; ++i) {
        int s = __builtin_amdgcn_readlane(sidx, k + i);
        v[i] = bf2f(bbh[(size_t)s * 64 + lane]);
      }
#pragma unroll
      for (int i = 0; i < 16; ++i) {
        float x = v[i];
        S += x;
        S2 = fmaf(x, x, S2);
        MN = fminf(MN, x);
        MX = fmaxf(MX, x);
      }
    }
    if (k < cnt) {
      float v[16];
      int m = cnt - k;                 // 1..15
#pragma unroll
      for (int i = 0; i < 16; ++i) {
        int kk = k + (i < m ? i : 0);  // clamp: duplicates are masked below
        int s = __builtin_amdgcn_readlane(sidx, kk);
        v[i] = bf2f(bbh[(size_t)s * 64 + lane]);
      }
#pragma unroll
      for (int i = 0; i < 16; ++i) {
        if (i < m) {
          float x = v[i];
          S += x;
          S2 = fmaf(x, x, S2);
          MN = fminf(MN, x);
          MX = fmaxf(MX, x);
        }
      }
    }
  }
  int d = hi - lo;
  bool valid = lane < FF;
  float mean, mnv, mxv, stdv;
  if (d > 0) {
    float inv = 1.f / (float)d;
    float m = S * inv;
    float vv = S2 * inv - m * m; vv = vv > 0.f ? vv : 0.f;
    stdv = sqrtf(vv + 1e-5f);
    float c = valid ? bf2f(cbh[(size_t)n * 64 + lane]) : 0.f;
    mean = c + m;
    mnv = c + MN;
    mxv = c + MX;
  } else {
    mean = mnv = mxv = 0.f;
    stdv = sqrtf(1e-5f);
  }
  short* row = agb + (size_t)n * 256;
  row[lane]       = valid ? f2bf(mean) : 0;
  row[64 + lane]  = valid ? f2bf(mnv) : 0;
  row[128 + lane] = valid ? f2bf(mxv) : 0;
  row[192 + lane] = valid ? f2bf(stdv) : 0;
  if (lane == 0) {
    float avg = scal[0] * (1.f / NN);
    float lg = lgc[n];
    ampatt[2 * n] = lg / avg;
    ampatt[2 * n + 1] = avg / lg;
  }
}

// ---------------- post GEMM: 128 nodes/block, 512 threads (8 waves), one-round residency ----------------
__global__ __launch_bounds__(512, 2) void k_gemm(const short* __restrict__ h, const float2* __restrict__ ab,
                                                 const short* __restrict__ agb, const float* __restrict__ ampatt,
                                                 const short* __restrict__ Abt, const float* __restrict__ bias2,
                                                 short* __restrict__ hout, float* __restrict__ bnsumR) {
  __shared__ short Bs[3][64][72];   // 27.6 KB
  int tid = threadIdx.x;
  int w = tid >> 6, lane = tid & 63;
  int q = lane >> 4, m16 = lane & 15;
  int n0 = blockIdx.x * 128 + w * 16;

  // A-fragments in registers
  int anode = n0 + m16;
  int nsafe = anode < NN ? anode : 0;
  bf16x8 afr[5][2];
  {
#pragma unroll
    for (int hh = 0; hh < 2; ++hh) {
      const short* srcp = h + (size_t)nsafe * 64 + hh * 32 + q * 8;
      afr[0][hh] = ab ? ldfrag_bn(srcp, ab, hh * 32 + q * 8) : *(const bf16x8*)srcp;
    }
    const short* arow = agb + (size_t)nsafe * 256;
#pragma unroll
    for (int c = 1; c <= 4; ++c)
#pragma unroll
      for (int hh = 0; hh < 2; ++hh)
        afr[c][hh] = *(const bf16x8*)(arow + (c - 1) * 64 + hh * 32 + q * 8);
  }

  f32x4 acc[3][4];
#pragma unroll
  for (int s = 0; s < 3; ++s)
#pragma unroll
    for (int ft = 0; ft < 4; ++ft) acc[s][ft] = (f32x4){0.f, 0.f, 0.f, 0.f};

  // B staging roles: first 4 waves only
  bool stager = tid < 256;
  int bf = tid >> 2;            // 0..63 for stagers
  int bko = (tid & 3) * 16;
  float4 rg[3][2];
  if (stager) {
    const float4* g = (const float4*)(Abt + (bf << 6) + bko);
    rg[0][0] = g[0]; rg[0][1] = g[1];
  }
  for (int ph = 0; ph < 5; ++ph) {
    int nslice = (ph == 0) ? 1 : 3;
    if (ph) __syncthreads();
    if (stager) {
      for (int s = 0; s < nslice; ++s) {
        *(float4*)&Bs[s][bf][bko] = rg[s][0];
        *(float4*)&Bs[s][bf][bko + 8] = rg[s][1];
      }
    }
    __syncthreads();
    if (stager && ph < 4) {
#pragma unroll
      for (int s = 0; s < 3; ++s) {
        int chunk = (ph + 1) + 4 * s;
        const float4* g = (const float4*)(Abt + (chunk << 12) + (bf << 6) + bko);
        rg[s][0] = g[0]; rg[s][1] = g[1];
      }
    }
    if (ph == 0) {
#pragma unroll
      for (int hh = 0; hh < 2; ++hh)
#pragma unroll
        for (int ft = 0; ft < 4; ++ft) {
          bf16x8 b = *(const bf16x8*)&Bs[0][ft * 16 + m16][hh * 32 + q * 8];
          acc[0][ft] = __builtin_amdgcn_mfma_f32_16x16x32_bf16(afr[0][hh], b, acc[0][ft], 0, 0, 0);
        }
    } else {
#pragma unroll
      for (int hh = 0; hh < 2; ++hh)
#pragma unroll
        for (int s = 0; s < 3; ++s)
#pragma unroll
          for (int ft = 0; ft < 4; ++ft) {
            bf16x8 b = *(const bf16x8*)&Bs[s][ft * 16 + m16][hh * 32 + q * 8];
            acc[s][ft] = __builtin_amdgcn_mfma_f32_16x16x32_bf16(afr[ph][hh], b, acc[s][ft], 0, 0, 0);
          }
    }
  }

  // epilogue: bf16 store (pad cols zeroed) + BN partials in fp32
  float sacc[4] = {0.f, 0.f, 0.f, 0.f};
  float qacc[4] = {0.f, 0.f, 0.f, 0.f};
#pragma unroll
  for (int r = 0; r < 4; ++r) {
    int node = n0 + q * 4 + r;
    if (node >= NN) continue;
    float2 aa = *(const float2*)(ampatt + 2 * node);
#pragma unroll
    for (int ft = 0; ft < 4; ++ft) {
      int col = ft * 16 + m16;
      float val = 0.f;
      if (col < FF) {
        val = acc[0][ft][r] + aa.x * acc[1][ft][r] + aa.y * acc[2][ft][r] + bias2[col];
        sacc[ft] += val;
        qacc[ft] = fmaf(val, val, qacc[ft]);
      }
      hout[node * 64 + col] = f2bf(val);
    }
  }
  // per-wave reduce: lanes sharing m16 (differ in bits 4,5) sum their 4 nodes
#pragma unroll
  for (int ft = 0; ft < 4; ++ft) {
    sacc[ft] += __shfl_xor(sacc[ft], 16);
    sacc[ft] += __shfl_xor(sacc[ft], 32);
    qacc[ft] += __shfl_xor(qacc[ft], 16);
    qacc[ft] += __shfl_xor(qacc[ft], 32);
  }
  // block-level reduce in LDS (Bs is dead after last MFMA phase), then 2
  // atomic wave-instructions per block.
  __syncthreads();                       // all waves done reading Bs
  float* red = (float*)&Bs[0][0][0];     // 8 waves x 128 floats = 4 KB
  if (lane < 16) {
#pragma unroll
    for (int ft = 0; ft < 4; ++ft) {
      red[w * 128 + ft * 16 + lane]      = sacc[ft];
      red[w * 128 + 64 + ft * 16 + lane] = qacc[ft];
    }
  }
  __syncthreads();
  if (tid < 128) {
    float v = 0.f;
#pragma unroll
    for (int i = 0; i < 8; ++i) v += red[i * 128 + tid];
    atomicAdd(&bnsumR[(blockIdx.x & 7) * 128 + tid], v);
  }
}

// ---------------- BN coeffs from 8 replicas ----------------
__global__ void k_bnab(const float* __restrict__ bnsumR, const float* __restrict__ gamma,
                       const float* __restrict__ beta, float2* __restrict__ ab, int l) {
  int f = threadIdx.x;
  float a = 0.f, b = 0.f;
  if (f < FF) {
    float s = 0.f, q = 0.f;
    for (int r = 0; r < 8; ++r) { s += bnsumR[r * 128 + f]; q += bnsumR[r * 128 + 64 + f]; }
    float mu = s * (1.f / NN);
    float vq = q * (1.f / NN) - mu * mu;
    float rs = rsqrtf((vq > 0.f ? vq : 0.f) + 1e-5f);
    a = rs * gamma[l * FF + f];
    b = beta[l * FF + f] - mu * a;
  }
  ab[f] = make_float2(a, b);
}

// ---------------- graph partial sums (fused BN+ReLU of last layer, bf16 h) ----------------
__global__ void k_gsum(const short* __restrict__ h, const float2* __restrict__ ab,
                       const int* __restrict__ batch, float* __restrict__ gsum) {
  int w = threadIdx.x >> 6, lane = threadIdx.x & 63;
  int fc = lane < FF ? lane : FF - 1;
  bool act = lane < FF;
  float2 p = ab[fc];
  int n0 = blockIdx.x * 256 + w * 64;
  if (n0 >= NN) return;
  int nEnd = n0 + 64 < NN ? n0 + 64 : NN;
  float acc = 0.f;
  int gcur = batch[n0];
  for (int n = n0; n < nEnd; ++n) {
    int g = batch[n];
    if (g != gcur) {
      if (act) atomicAdd(&gsum[gcur * 64 + lane], acc);
      acc = 0.f; gcur = g;
    }
    float v = bf2f(h[n * 64 + fc]);
    acc += fmaxf(fmaf(v, p.x, p.y), 0.f);
  }
  if (act) atomicAdd(&gsum[gcur * 64 + lane], acc);
}

// ---------------- final MLP ----------------
__global__ void k_mlp(const float* __restrict__ gsum, const float* __restrict__ W1,
                      const float* __restrict__ b1, const float* __restrict__ W2,
                      const float* __restrict__ b2, float* __restrict__ out) {
  int g = threadIdx.x;
  if (g >= NG) return;
  float gv[FF];
#pragma unroll
  for (int f = 0; f < FF; ++f) gv[f] = gsum[g * 64 + f];
  float r = b2[0];
  for (int j = 0; j < 25; ++j) {
    float a = b1[j];
#pragma unroll
    for (int f = 0; f < FF; ++f) a = fmaf(gv[f], W1[f * 25 + j], a);
    r += fmaxf(a, 0.f) * W2[j];
  }
  out[g] = r;
}

extern "C" void kernel_launch(void* const* d_in, const int* in_sizes, int n_in,
                              void* d_out, int out_size, void* d_ws, size_t ws_size,
                              hipStream_t stream) {
  const float* x     = (const float*)d_in[0];
  const int*   ei    = (const int*)d_in[1];
  const int*   src   = ei;
  const int*   dst   = ei + NE;
  const int*   batch = (const int*)d_in[2];
  const float* Wg    = (const float*)d_in[3];
  const float* bg    = (const float*)d_in[4];
  const float* preW  = (const float*)d_in[5];
  const float* preb  = (const float*)d_in[6];
  const float* postW = (const float*)d_in[7];
  const float* postb = (const float*)d_in[8];
  const float* linW  = (const float*)d_in[9];
  const float* linb  = (const float*)d_in[10];
  const float* gamma = (const float*)d_in[11];
  const float* beta  = (const float*)d_in[12];
  const float* W1    = (const float*)d_in[13];
  const float* b1    = (const float*)d_in[14];
  const float* W2    = (const float*)d_in[15];
  const float* b2    = (const float*)d_in[16];
  float* out = (float*)d_out;

  char* W = (char*)d_ws;
  int*    bcnt   = (int*)(W + 0);            // 2048 (391 used)
  int*    bbase  = (int*)(W + 2048);         // 2048
  int*    off    = (int*)(W + 400384);       // 400896
  float*  dinv   = (float*)(W + 807424);     // 400384
  float*  lgc    = (float*)(W + 1207808);    // 400384
  float*  scal   = (float*)(W + 1608192);    // 512
  float*  bnsum  = (float*)(W + 1608704);    // 12288
  float2* ab     = (float2*)(W + 1620992);   // 1536
  float*  Af     = (float*)(W + 1622528);    // 390144
  float*  bias2  = (float*)(W + 2012672);    // 1024
  short*  Abt    = (short*)(W + 2013696);    // 319488
  short*  Pbt    = (short*)(W + 2333184);    // 49152
  int*    ssrc   = (int*)(W + 8782336);      // 6400000
  short*  hA     = (short*)(W + 15182336);   // 12800256 (bf16 [node][64])
  short*  hB     = (short*)(W + 27982592);   // 12800256
  short*  cbh    = (short*)(W + 40782848);   // 12800256 (bf16 [node][64])
  short*  bbh    = (short*)(W + 53583104);   // 12800256 (bf16 [node][64]; also GCN p)
  short*  agb    = (short*)(W + 66383360);   // 51200256 (bf16 [node][256])
  float*  ampatt = (float*)(W + 117583616);  // 800256
  float*  gsum   = (float*)(W + 118383872);  // 16384   (total ~118.4 MB)
  // tmp (bucket segments, 391*8192*4 = 12.8 MB) aliases the agb region:
  // its lifetime (k_bucket2 -> k_bsort2) ends before k_agg first writes agb,
  // and k_agg fully rewrites every agb row each layer (stream-ordered).
  unsigned* tmp  = (unsigned*)agb;

  hipMemsetAsync(bcnt, 0, 2048, stream);
  hipMemsetAsync(scal, 0, 12800, stream);   // scal + bnsum
  hipMemsetAsync(gsum, 0, 16384, stream);

  k_bucket2<<<(NE + 4095) / 4096, 256, 0, stream>>>(src, dst, bcnt, tmp);
  k_bscan<<<1, 512, 0, stream>>>(bcnt, bbase, off);
  k_bsort2<<<NBUCK, 256, 0, stream>>>(tmp, bcnt, bbase, off, ssrc, dinv, lgc, scal);
  k_fusew<<<(3 * 651 + 3) / 4, 256, 0, stream>>>(postW, postb, linW, linb, Af, bias2);
  k_packA<<<(3 * 13 * 64 * 64 + 255) / 256, 256, 0, stream>>>(Af, Abt);
  k_packP<<<(NL * 2 * 64 * 64 + 255) / 256, 256, 0, stream>>>(preW, Pbt);

  k_gcnpre<<<NN / 4, 256, 0, stream>>>(x, Wg, dinv, bbh);
  k_gcnagg<<<NN / 4, 256, 0, stream>>>(bbh, off, ssrc, dinv, bg, hA);

  short* hin = hA;
  short* hout = hB;
  for (int l = 0; l < NL; ++l) {
    const float2* abl = (l == 0) ? nullptr : (ab + (l - 1) * 64);
    k_preM<<<(NN + 63) / 64, 256, 0, stream>>>(hin, abl, Pbt, preb, cbh, bbh, l);
    k_agg<<<NN / 4, 256, 0, stream>>>(bbh, cbh, off, ssrc, lgc, scal, agb, ampatt);
    k_gemm<<<(NN + 127) / 128, 512, 0, stream>>>(hin, abl, agb, ampatt,
                                                 Abt + l * 13 * 4096, bias2 + l * 64, hout,
                                                 bnsum + l * 1024);
    k_bnab<<<1, 64, 0, stream>>>(bnsum + l * 1024, gamma, beta, ab + l * 64, l);
    short* t = hin; hin = hout; hout = t;
  }
  k_gsum<<<NBUCK, 256, 0, stream>>>(hin, ab + 2 * 64, batch, gsum);
  k_mlp<<<1, 64, 0, stream>>>(gsum, W1, b1, W2, b2, out);
}